// Round 6
// baseline (53.174 us; speedup 1.0000x reference)
//
#include <hip/hip_runtime.h>

#define PAD 4
#define B_ 64
#define C_ 9
#define H_ 256
#define W_ 256
#define PEXT 264           // padded extent (both axes)
#define QROWS 16           // output rows per quarter
#define SROWS 18           // max staged rows per quarter
#define NBLK (B_ * C_ * (H_ / 64))   // 2304 = 9 blocks/CU, divisible by 8

// Block = 512 threads (8 waves) owning a 64-row x 256-col tile of one plane,
// processed as four 16-row quarters with a rolling 2-buffer pipeline:
//   stage(q0,A); bar; stage(q1,B); compute(q0,A); bar;
//   stage(q2,A); compute(q1,B);    bar; stage(q3,B); compute(q2,A); bar;
//   compute(q3,B)
// 3/4 of the staging latency hides under compute; quarter-overlap rows are
// re-issued from L2 (just fetched, co-XCD), so HBM fetch ~= one input read.
//
// LDS holds PURE source rows: x-replicate pad folded into tap weights (merge
// weights when both taps clamp to the same source column), y-replicate by
// clamping the staged row, zeros-padding by zeroing weights vs [0,263].
// Coordinate math identical to rounds 1-5: ix = 0.5 + shift + j*(262/255).
__global__ __launch_bounds__(512, 8) void RandomShiftsAug_kernel(
    const float* __restrict__ x,
    const int* __restrict__ shift_x,
    const int* __restrict__ shift_y,
    float* __restrict__ out)
{
    __shared__ float sm[2][SROWS][W_];   // 36864 B -> 4 blocks/CU, 32 waves/CU

    const int tid  = threadIdx.x;
    const int lane = tid & 63;
    const int wv   = tid >> 6;           // 0..7

    // XCD-bijective swizzle (NBLK % 8 == 0): adjacent work ids -> same XCD.
    const int wid  = (blockIdx.x & 7) * (NBLK / 8) + (blockIdx.x >> 3);

    const int bc   = wid >> 2;           // plane id (b*C + c)
    const int I0   = (wid & 3) << 6;     // 64-row tile base
    const int b    = bc / C_;

    const float STEP = 262.0f / 255.0f;
    const float sx = (float)shift_x[b];
    const float sy = (float)shift_y[b];
    const float xbase = 0.5f + sx;
    const float ybase = 0.5f + sy;

    const float* __restrict__ plane = x + (size_t)bc * (size_t)(H_ * W_);

    // ---- x-side precompute: 4 interleaved cols/lane, pad folded into weights
    float wx0[4], wx1[4];
    int cx[4];
    #pragma unroll
    for (int c = 0; c < 4; ++c) {
        const int j = lane + 64 * c;
        const float ixv = fmaf((float)j, STEP, xbase);
        const float fx  = floorf(ixv);
        const int   px0 = (int)fx;              // >= 0 always (ix >= 0.5)
        float w1 = ixv - fx;
        float w0 = 1.0f - w1;
        if (px0 > PEXT - 1)     w0 = 0.0f;      // zeros padding
        if (px0 + 1 > PEXT - 1) w1 = 0.0f;
        const int s = px0 - PAD;                // desired source col of tap0
        if (s < 0)    { w0 += w1; w1 = 0.0f; }  // both taps -> src col 0
        if (s >= 255) { w1 += w0; w0 = 0.0f; }  // both taps -> src col 255
        cx[c]  = min(max(s, 0), 254);           // fused pair reads (cx, cx+1)
        wx0[c] = w0;
        wx1[c] = w1;
    }

    // ---- stage quarter q into buffer buf: pure global_load_lds, 16B/lane
    auto stage = [&](int q, int buf) {
        const int i0   = I0 + q * QROWS;
        const int base = (int)floorf(fmaf((float)i0, STEP, ybase));
        const int n    = (int)floorf(fmaf((float)(i0 + QROWS - 1), STEP, ybase))
                         + 2 - base;            // 17 or 18
        for (int s = wv; s < n; s += 8) {
            const int rs = min(max(base + s - PAD, 0), H_ - 1);
            const float* src = plane + rs * W_ + lane * 4;
            __builtin_amdgcn_global_load_lds(
                (const __attribute__((address_space(1))) void*)src,
                (__attribute__((address_space(3))) void*)&sm[buf][s][0],
                16, 0, 0);
        }
    };

    // ---- compute quarter q from buffer buf: 2 rows per wave, 4 cols per lane
    auto compute = [&](int q, int buf) {
        const int i0   = I0 + q * QROWS;
        const int base = (int)floorf(fmaf((float)i0, STEP, ybase));
        #pragma unroll
        for (int m = 0; m < 2; ++m) {
            const int i = i0 + wv * 2 + m;                  // wave-uniform row
            const float iyv = fmaf((float)i, STEP, ybase);
            const float fy  = floorf(iyv);
            const int   py0 = (int)fy;
            float wy1 = iyv - fy;
            float wy0 = 1.0f - wy1;
            if (py0 > PEXT - 1)     wy0 = 0.0f;
            if (py0 + 1 > PEXT - 1) wy1 = 0.0f;
            const int s0 = py0 - base;                      // in [0, n-2]
            const float* __restrict__ r0p = &sm[buf][s0][0];
            const float* __restrict__ r1p = &sm[buf][s0 + 1][0];
            float* __restrict__ orow = out + ((size_t)(bc * H_ + i)) * (size_t)W_;

            #pragma unroll
            for (int c = 0; c < 4; ++c) {
                const int rd = cx[c];
                const float v00 = r0p[rd], v01 = r0p[rd + 1];   // ds_read2_b32
                const float v10 = r1p[rd], v11 = r1p[rd + 1];   // ds_read2_b32
                const float a0 = fmaf(v00, wx0[c], v01 * wx1[c]);
                const float a1 = fmaf(v10, wx0[c], v11 * wx1[c]);
                orow[lane + 64 * c] = fmaf(a0, wy0, a1 * wy1);
            }
        }
    };

    stage(0, 0);
    __syncthreads();          // buf0 ready (vmcnt drained)
    stage(1, 1);              // hide under compute(q0)
    compute(0, 0);
    __syncthreads();          // buf1 ready; buf0 readers done
    stage(2, 0);              // hide under compute(q1)
    compute(1, 1);
    __syncthreads();          // buf0 ready; buf1 readers done
    stage(3, 1);              // hide under compute(q2)
    compute(2, 0);
    __syncthreads();          // buf1 ready
    compute(3, 1);
}

extern "C" void kernel_launch(void* const* d_in, const int* in_sizes, int n_in,
                              void* d_out, int out_size, void* d_ws, size_t ws_size,
                              hipStream_t stream) {
    const float* x       = (const float*)d_in[0];
    const int*   shift_x = (const int*)d_in[1];
    const int*   shift_y = (const int*)d_in[2];
    float*       out     = (float*)d_out;

    RandomShiftsAug_kernel<<<NBLK, 512, 0, stream>>>(x, shift_x, shift_y, out);
}

// Round 7
// 51.454 us; speedup vs baseline: 1.0334x; 1.0334x over previous
//
#include <hip/hip_runtime.h>

#define PAD 4
#define B_ 64
#define C_ 9
#define H_ 256
#define W_ 256
#define PEXT 264           // padded extent (both axes)
#define TILE_R 16          // output rows per block
#define SROWS 18           // max staged rows per block
#define NBLK (B_ * C_ * (H_ / TILE_R))   // 9216, divisible by 8

// Round-7 consolidation: R4's winning structure (256 threads, 16-row tile,
// ONE barrier, 18KB LDS -> 8 blocks/CU = 32 waves/CU) with:
//  - x-replicate pad folded into tap weights (merge weights when both taps
//    clamp to the same source col) -> staging is PURE global_load_lds,
//    no edge gathers, no ds_writes, no second barrier;
//  - dwordx2 stores: lane owns col pairs {2l,2l+1} and {2l+128,2l+129}
//    (store count halved; ds_read2 access stride ~2.05 dwords stays ~2-way
//    bank aliasing = free).
// y-replicate via clamped staged row; zeros-padding by zeroing weights vs
// [0,263]. Coordinate math identical to rounds 1-6: ix = 0.5+shift+j*(262/255).
__global__ __launch_bounds__(256) void RandomShiftsAug_kernel(
    const float* __restrict__ x,
    const int* __restrict__ shift_x,
    const int* __restrict__ shift_y,
    float* __restrict__ out)
{
    __shared__ float sm[SROWS][W_];     // 18432 B -> 8 blocks/CU

    const int tid  = threadIdx.x;
    const int lane = tid & 63;
    const int wv   = tid >> 6;          // 0..3

    // XCD-bijective swizzle (NBLK % 8 == 0): adjacent work ids -> same XCD.
    const int wid  = (blockIdx.x & 7) * (NBLK / 8) + (blockIdx.x >> 3);

    const int bc   = wid >> 4;          // plane id (b*C + c)
    const int i0   = (wid & 15) << 4;   // 16-row tile base
    const int b    = bc / C_;

    const float STEP = 262.0f / 255.0f;
    const float sx = (float)shift_x[b];
    const float sy = (float)shift_y[b];
    const float xbase = 0.5f + sx;
    const float ybase = 0.5f + sy;

    const float* __restrict__ plane = x + (size_t)bc * (size_t)(H_ * W_);

    // staged padded-row range (block-uniform): 17 or 18 rows
    const int sr_base = (int)floorf(fmaf((float)i0, STEP, ybase));
    const int srows   = (int)floorf(fmaf((float)(i0 + TILE_R - 1), STEP, ybase))
                        + 2 - sr_base;

    // ---- stage: pure global_load_lds, 16B/lane, rows round-robin over waves
    for (int s = wv; s < srows; s += 4) {
        const int rs = min(max(sr_base + s - PAD, 0), H_ - 1);
        const float* src = plane + rs * W_ + lane * 4;
        __builtin_amdgcn_global_load_lds(
            (const __attribute__((address_space(1))) void*)src,
            (__attribute__((address_space(3))) void*)&sm[s][0],
            16, 0, 0);
    }

    // ---- x-side precompute while loads are in flight:
    // cols j = 2*lane + (c&1) + 128*(c>>1), pad folded into weights
    float wx0[4], wx1[4];
    int cx[4];
    #pragma unroll
    for (int c = 0; c < 4; ++c) {
        const int j = 2 * lane + (c & 1) + 128 * (c >> 1);
        const float ixv = fmaf((float)j, STEP, xbase);
        const float fx  = floorf(ixv);
        const int   px0 = (int)fx;              // >= 0 always (ix >= 0.5)
        float w1 = ixv - fx;
        float w0 = 1.0f - w1;
        if (px0 > PEXT - 1)     w0 = 0.0f;      // zeros padding
        if (px0 + 1 > PEXT - 1) w1 = 0.0f;
        const int s = px0 - PAD;                // desired source col of tap0
        if (s < 0)    { w0 += w1; w1 = 0.0f; }  // both taps -> src col 0
        if (s >= 255) { w1 += w0; w0 = 0.0f; }  // both taps -> src col 255
        cx[c]  = min(max(s, 0), 254);           // fused pair reads (cx, cx+1)
        wx0[c] = w0;
        wx1[c] = w1;
    }

    __syncthreads();   // buf ready (drains vmcnt)

    // ---- compute: 4 rows per wave, 4 cols per lane, dwordx2 stores
    #pragma unroll
    for (int m = 0; m < 4; ++m) {
        const int i = i0 + wv * 4 + m;                      // wave-uniform row
        const float iyv = fmaf((float)i, STEP, ybase);
        const float fy  = floorf(iyv);
        const int   py0 = (int)fy;
        float wy1 = iyv - fy;
        float wy0 = 1.0f - wy1;
        if (py0 > PEXT - 1)     wy0 = 0.0f;
        if (py0 + 1 > PEXT - 1) wy1 = 0.0f;
        const int s0 = py0 - sr_base;                       // in [0, srows-2]
        const float* __restrict__ r0p = &sm[s0][0];
        const float* __restrict__ r1p = &sm[s0 + 1][0];
        float2* __restrict__ orow2 =
            (float2*)(out + ((size_t)(bc * H_ + i)) * (size_t)W_);

        #pragma unroll
        for (int p = 0; p < 2; ++p) {
            const int c0 = 2 * p, c1 = 2 * p + 1;
            const int rd0 = cx[c0], rd1 = cx[c1];
            const float v00 = r0p[rd0], v01 = r0p[rd0 + 1];   // ds_read2_b32
            const float v02 = r0p[rd1], v03 = r0p[rd1 + 1];   // ds_read2_b32
            const float v10 = r1p[rd0], v11 = r1p[rd0 + 1];   // ds_read2_b32
            const float v12 = r1p[rd1], v13 = r1p[rd1 + 1];   // ds_read2_b32

            const float a0 = fmaf(v00, wx0[c0], v01 * wx1[c0]);
            const float b0 = fmaf(v10, wx0[c0], v11 * wx1[c0]);
            const float a1 = fmaf(v02, wx0[c1], v03 * wx1[c1]);
            const float b1 = fmaf(v12, wx0[c1], v13 * wx1[c1]);

            float2 o;
            o.x = fmaf(a0, wy0, b0 * wy1);
            o.y = fmaf(a1, wy0, b1 * wy1);
            orow2[lane + 64 * p] = o;
        }
    }
}

extern "C" void kernel_launch(void* const* d_in, const int* in_sizes, int n_in,
                              void* d_out, int out_size, void* d_ws, size_t ws_size,
                              hipStream_t stream) {
    const float* x       = (const float*)d_in[0];
    const int*   shift_x = (const int*)d_in[1];
    const int*   shift_y = (const int*)d_in[2];
    float*       out     = (float*)d_out;

    RandomShiftsAug_kernel<<<NBLK, 256, 0, stream>>>(x, shift_x, shift_y, out);
}